// Round 1
// baseline (627.833 us; speedup 1.0000x reference)
//
#include <hip/hip_runtime.h>
#include <hip/hip_bf16.h>

typedef unsigned short u16;
typedef __bf16 bf16x8 __attribute__((ext_vector_type(8)));
typedef float f32x4 __attribute__((ext_vector_type(4)));

__device__ __forceinline__ u16 f2bf(float f) {
    union { float f; unsigned int u; } v; v.f = f;
    unsigned int u = v.u;
    unsigned int r = (u + 0x7fffu + ((u >> 16) & 1u)) >> 16;
    return (u16)r;
}
__device__ __forceinline__ float bf2f(u16 b) {
    union { unsigned int u; float f; } v; v.u = ((unsigned int)b) << 16;
    return v.f;
}

__device__ __forceinline__ void glds16(const u16* g, u16* l) {
    __builtin_amdgcn_global_load_lds(
        (__attribute__((address_space(1))) void*)(g),
        (__attribute__((address_space(3))) void*)(l), 16, 0, 0);
}

// ---------------- cast fp32 -> bf16 (vectorized) ----------------
__global__ __launch_bounds__(256) void cast_bf16_kernel(const float* __restrict__ src,
                                                        u16* __restrict__ dst, int n4) {
    int i = blockIdx.x * 256 + threadIdx.x;
    if (i >= n4) return;
    float4 v = ((const float4*)src)[i];
    ushort4 o;
    o.x = f2bf(v.x); o.y = f2bf(v.y); o.z = f2bf(v.z); o.w = f2bf(v.w);
    ((ushort4*)dst)[i] = o;
}

// ---------------- transpose+cast weights: WT[n][k] = W[k][n] ----------------
__global__ __launch_bounds__(256) void transpose_cast_kernel(
    const float* __restrict__ Wq, const float* __restrict__ Wk, const float* __restrict__ Wv,
    const float* __restrict__ Wg, const float* __restrict__ Wo,
    u16* __restrict__ WqT, u16* __restrict__ WkvT, u16* __restrict__ WgT, u16* __restrict__ WoT) {
    __shared__ float tile[32][33];
    const float* src; u16* dst;
    switch (blockIdx.z) {
        case 0: src = Wq; dst = WqT; break;
        case 1: src = Wk; dst = WkvT; break;
        case 2: src = Wv; dst = WkvT + (size_t)1024 * 1024; break;
        case 3: src = Wg; dst = WgT; break;
        default: src = Wo; dst = WoT; break;
    }
    int n0 = blockIdx.x * 32, k0 = blockIdx.y * 32;
    int tx = threadIdx.x, ty = threadIdx.y;   // (32, 8)
    #pragma unroll
    for (int j = 0; j < 4; j++)
        tile[ty + j * 8][tx] = src[(size_t)(k0 + ty + j * 8) * 1024 + n0 + tx];
    __syncthreads();
    #pragma unroll
    for (int j = 0; j < 4; j++)
        dst[(size_t)(n0 + ty + j * 8) * 1024 + k0 + tx] = f2bf(tile[tx][ty + j * 8]);
}

// ---------------- bf16 MFMA GEMM: C[M,N] = A[M,1024] @ B[N,1024]^T ----------------
// 128x128 tile, BK=64, 4 waves (2x2), 16x16x32 MFMA, global_load_lds w/ XOR-swizzled source.
// EPI 0: write bf16 C (ldc).  EPI 2: gate (g=acc+bias[n]; C=bf16(mul*sigmoid(g))).
// EPI 3: fp32 C = acc + bias[n] + add[m*1024+n].
template <int EPI>
__global__ __launch_bounds__(256) void gemm_bf16(
    const u16* __restrict__ A, const u16* __restrict__ B, int ldc,
    u16* __restrict__ Cbf, const float* __restrict__ bias,
    const u16* __restrict__ mul_src, const float* __restrict__ add_src,
    float* __restrict__ Cf) {
    constexpr int K = 1024;
    const int tid = threadIdx.x;
    const int w = tid >> 6, l = tid & 63;
    const int lr = l & 15, lg = l >> 4;
    const int wr = w >> 1, wc = w & 1;
    const int m0 = blockIdx.y * 128, n0 = blockIdx.x * 128;

    __shared__ u16 As[128 * 64];
    __shared__ u16 Bs[128 * 64];

    const f32x4 fz = {0.f, 0.f, 0.f, 0.f};
    f32x4 acc[4][4];
    #pragma unroll
    for (int i = 0; i < 4; i++)
        #pragma unroll
        for (int j = 0; j < 4; j++) acc[i][j] = fz;

    const int lane_row = l >> 3;                 // 0..7 within an 8-row issue
    const int lane_sl  = l & 7;
    const int src_ch   = lane_sl ^ lane_row;     // T2 swizzle (pre-swizzled source)
    const u16* Ab = A + (size_t)(m0 + w * 32 + lane_row) * K + src_ch * 8;
    const u16* Bb = B + (size_t)(n0 + w * 32 + lane_row) * K + src_ch * 8;

    for (int kt = 0; kt < K; kt += 64) {
        __syncthreads();
        #pragma unroll
        for (int j = 0; j < 4; j++) {
            glds16(Ab + (size_t)j * 8 * K + kt, As + (w * 32 + j * 8) * 64);
            glds16(Bb + (size_t)j * 8 * K + kt, Bs + (w * 32 + j * 8) * 64);
        }
        __syncthreads();
        #pragma unroll
        for (int kk = 0; kk < 2; kk++) {
            bf16x8 af[4], bfr[4];
            #pragma unroll
            for (int mi = 0; mi < 4; mi++) {
                int row = wr * 64 + mi * 16 + lr;
                int ch = (kk * 4 + lg) ^ (row & 7);
                af[mi] = *(const bf16x8*)(As + row * 64 + ch * 8);
            }
            #pragma unroll
            for (int ni = 0; ni < 4; ni++) {
                int row = wc * 64 + ni * 16 + lr;
                int ch = (kk * 4 + lg) ^ (row & 7);
                bfr[ni] = *(const bf16x8*)(Bs + row * 64 + ch * 8);
            }
            #pragma unroll
            for (int mi = 0; mi < 4; mi++)
                #pragma unroll
                for (int ni = 0; ni < 4; ni++)
                    acc[mi][ni] = __builtin_amdgcn_mfma_f32_16x16x32_bf16(
                        af[mi], bfr[ni], acc[mi][ni], 0, 0, 0);
        }
    }

    #pragma unroll
    for (int mi = 0; mi < 4; mi++) {
        #pragma unroll
        for (int ni = 0; ni < 4; ni++) {
            #pragma unroll
            for (int r = 0; r < 4; r++) {
                int gm = m0 + wr * 64 + mi * 16 + lg * 4 + r;
                int gn = n0 + wc * 64 + ni * 16 + lr;
                float v = acc[mi][ni][r];
                if (EPI == 0) {
                    Cbf[(size_t)gm * ldc + gn] = f2bf(v);
                } else if (EPI == 2) {
                    float g = v + bias[gn];
                    float a = bf2f(mul_src[(size_t)gm * ldc + gn]);
                    float sg = 1.f / (1.f + __expf(-g));
                    Cbf[(size_t)gm * ldc + gn] = f2bf(a * sg);
                } else {
                    Cf[(size_t)gm * ldc + gn] = v + bias[gn] + add_src[(size_t)gm * ldc + gn];
                }
            }
        }
    }
}

// ---------------- q_summary: mean over Q of q_bf per (b,h,d) ----------------
__global__ __launch_bounds__(256) void qsum_kernel(const u16* __restrict__ q_bf,
                                                   float* __restrict__ qsum) {
    int bh = blockIdx.x, b = bh >> 4, h = bh & 15;
    int tid = threadIdx.x, d = tid & 63, c = tid >> 6;
    const u16* base = q_bf + ((size_t)b * 2048 + c) * 1024 + h * 64 + d;
    float acc = 0.f;
    for (int qi = c; qi < 2048; qi += 4) { acc += bf2f(*base); base += 4 * 1024; }
    __shared__ float red[256];
    red[tid] = acc;
    __syncthreads();
    if (tid < 64)
        qsum[bh * 64 + tid] = (red[tid] + red[tid + 64] + red[tid + 128] + red[tid + 192]) * (1.f / 2048.f);
}

// ---------------- selection scores: score[bh][kv] = scale * qsum . k ----------------
__global__ __launch_bounds__(256) void score_kernel(const u16* __restrict__ kv_bf,
                                                    const float* __restrict__ qsum,
                                                    float* __restrict__ score) {
    int bh = blockIdx.y, b = bh >> 4, h = bh & 15;
    __shared__ float qs[64];
    if (threadIdx.x < 64) qs[threadIdx.x] = qsum[bh * 64 + threadIdx.x];
    __syncthreads();
    int kv = blockIdx.x * 256 + threadIdx.x;
    const u16* kr = kv_bf + ((size_t)(b * 16384 + kv)) * 2048 + h * 64;
    float acc = 0.f;
    #pragma unroll
    for (int c = 0; c < 8; c++) {
        uint4 u = *(const uint4*)(kr + c * 8);
        const u16* p = (const u16*)&u;
        #pragma unroll
        for (int j = 0; j < 8; j++) acc += bf2f(p[j]) * qs[c * 8 + j];
    }
    score[(size_t)bh * 16384 + kv] = acc * 0.125f;
}

// ---------------- radix top-2048 select per (b,h) ----------------
__global__ __launch_bounds__(256) void select_kernel(const float* __restrict__ score,
                                                     int* __restrict__ sel_idx) {
    int bh = blockIdx.x;
    const float* sc = score + (size_t)bh * 16384;
    __shared__ int hist[256];
    __shared__ int bc[4];   // prefix, want, ctr_gt, ctr_eq
    int tid = threadIdx.x;
    if (tid == 0) { bc[0] = 0; bc[1] = 2048; bc[2] = 0; bc[3] = 0; }
    __syncthreads();
    for (int shift = 24; shift >= 0; shift -= 8) {
        hist[tid] = 0;
        __syncthreads();
        unsigned int prefix = (unsigned int)bc[0];
        unsigned int hi_mask = (shift == 24) ? 0u : (0xFFFFFFFFu << (shift + 8));
        for (int i = tid; i < 16384; i += 256) {
            unsigned int b = __float_as_uint(sc[i]);
            unsigned int ui = (b & 0x80000000u) ? ~b : (b | 0x80000000u);
            if ((ui & hi_mask) == (prefix & hi_mask))
                atomicAdd(&hist[(ui >> shift) & 0xff], 1);
        }
        __syncthreads();
        if (tid == 0) {
            int want = bc[1], acc = 0, d = 0;
            for (int dd = 255; dd >= 0; dd--) {
                acc += hist[dd];
                if (acc >= want) { d = dd; break; }
            }
            bc[1] = want - (acc - hist[d]);
            bc[0] = (int)(prefix | ((unsigned int)d << shift));
        }
        __syncthreads();
    }
    unsigned int uthr = (unsigned int)bc[0];
    int n_eq = bc[1];
    int base_eq = 2048 - n_eq;
    int* out = sel_idx + (size_t)bh * 2048;
    for (int i = tid; i < 16384; i += 256) {
        unsigned int b = __float_as_uint(sc[i]);
        unsigned int ui = (b & 0x80000000u) ? ~b : (b | 0x80000000u);
        if (ui > uthr) {
            int p = atomicAdd(&bc[2], 1);
            out[p] = i;
        } else if (ui == uthr) {
            int p = atomicAdd(&bc[3], 1);
            if (p < n_eq) out[base_eq + p] = i;
        }
    }
}

// ---------------- gather V selected, transposed: v_selT[bh][d][t] ----------------
__global__ __launch_bounds__(256) void gather_vt_kernel(const u16* __restrict__ kv_bf,
                                                        const int* __restrict__ sel_idx,
                                                        u16* __restrict__ v_selT) {
    int bh = blockIdx.y, b = bh >> 4, h = bh & 15;
    int t0 = blockIdx.x * 64, tid = threadIdx.x;
    __shared__ u16 tile[64][72];
    __shared__ int idx[64];
    if (tid < 64) idx[tid] = sel_idx[(size_t)bh * 2048 + t0 + tid];
    __syncthreads();
    {
        int t = tid >> 2, dc = tid & 3;
        const u16* src = kv_bf + ((size_t)(b * 16384 + idx[t])) * 2048 + 1024 + h * 64 + dc * 16;
        *(uint4*)&tile[t][dc * 16]     = *(const uint4*)src;
        *(uint4*)&tile[t][dc * 16 + 8] = *(const uint4*)(src + 8);
    }
    __syncthreads();
    u16* dst = v_selT + (size_t)bh * 64 * 2048;
    #pragma unroll
    for (int rep = 0; rep < 2; rep++) {
        int ch = tid + rep * 256;   // 0..511
        int d = ch >> 3, c = ch & 7;
        union { u16 u[8]; uint4 v; } tmp;
        #pragma unroll
        for (int j = 0; j < 8; j++) tmp.u[j] = tile[c * 8 + j][d];
        *(uint4*)(dst + (size_t)d * 2048 + t0 + c * 8) = tmp.v;
    }
}

// ---------------- flash attention over selected KV ----------------
__global__ __launch_bounds__(256) void attn_kernel(
    const u16* __restrict__ q_bf, const u16* __restrict__ kv_bf,
    const u16* __restrict__ v_selT, const int* __restrict__ sel_idx,
    u16* __restrict__ attn_out) {
    const int bh = blockIdx.y, b = bh >> 4, h = bh & 15;
    const int q0 = blockIdx.x * 64;
    const int tid = threadIdx.x, w = tid >> 6, l = tid & 63;
    const int lr = l & 15, lg = l >> 4;
    const float LOG2E = 1.44269504088896f;

    __shared__ int idx_lds[2048];
    __shared__ u16 k_lds[64][72];
    __shared__ u16 vt_lds[64][72];
    __shared__ u16 p_lds[4][16][72];

    for (int i = tid; i < 2048; i += 256) idx_lds[i] = sel_idx[(size_t)bh * 2048 + i];

    const u16* qb = q_bf + ((size_t)b * 2048 + q0 + w * 16 + lr) * 1024 + h * 64;
    bf16x8 qf0 = *(const bf16x8*)(qb + lg * 8);
    bf16x8 qf1 = *(const bf16x8*)(qb + 32 + lg * 8);

    const f32x4 fz = {0.f, 0.f, 0.f, 0.f};
    f32x4 o[4];
    #pragma unroll
    for (int f = 0; f < 4; f++) o[f] = fz;
    float m_run[4] = {-1e30f, -1e30f, -1e30f, -1e30f};
    float l_run[4] = {0.f, 0.f, 0.f, 0.f};

    const u16* kb  = kv_bf + (size_t)b * 16384 * 2048 + h * 64;
    const u16* vtb = v_selT + (size_t)bh * 64 * 2048;
    const int strow = tid >> 2, stch = tid & 3;

    __syncthreads();

    #pragma unroll 1
    for (int it = 0; it < 32; ++it) {
        const int t0 = it * 64;
        {
            int kvi = idx_lds[t0 + strow];
            const u16* src = kb + (size_t)kvi * 2048 + stch * 16;
            *(uint4*)&k_lds[strow][stch * 16]     = *(const uint4*)src;
            *(uint4*)&k_lds[strow][stch * 16 + 8] = *(const uint4*)(src + 8);
            const u16* vsrc = vtb + (size_t)strow * 2048 + t0 + stch * 16;
            *(uint4*)&vt_lds[strow][stch * 16]     = *(const uint4*)vsrc;
            *(uint4*)&vt_lds[strow][stch * 16 + 8] = *(const uint4*)(vsrc + 8);
        }
        __syncthreads();

        f32x4 s[4];
        #pragma unroll
        for (int c = 0; c < 4; c++) s[c] = fz;
        #pragma unroll
        for (int c = 0; c < 4; c++) {
            bf16x8 kf = *(const bf16x8*)(&k_lds[c * 16 + lr][lg * 8]);
            s[c] = __builtin_amdgcn_mfma_f32_16x16x32_bf16(qf0, kf, s[c], 0, 0, 0);
        }
        #pragma unroll
        for (int c = 0; c < 4; c++) {
            bf16x8 kf = *(const bf16x8*)(&k_lds[c * 16 + lr][32 + lg * 8]);
            s[c] = __builtin_amdgcn_mfma_f32_16x16x32_bf16(qf1, kf, s[c], 0, 0, 0);
        }

        float alpha[4];
        #pragma unroll
        for (int r = 0; r < 4; r++) {
            float mx = fmaxf(fmaxf(s[0][r], s[1][r]), fmaxf(s[2][r], s[3][r]));
            mx = fmaxf(mx, __shfl_xor(mx, 1));
            mx = fmaxf(mx, __shfl_xor(mx, 2));
            mx = fmaxf(mx, __shfl_xor(mx, 4));
            mx = fmaxf(mx, __shfl_xor(mx, 8));
            float mn = fmaxf(m_run[r], mx * 0.125f);
            alpha[r] = exp2f((m_run[r] - mn) * LOG2E);
            m_run[r] = mn;
        }
        float rs[4] = {0.f, 0.f, 0.f, 0.f};
        #pragma unroll
        for (int c = 0; c < 4; c++) {
            #pragma unroll
            for (int r = 0; r < 4; r++) {
                float p = exp2f((s[c][r] * 0.125f - m_run[r]) * LOG2E);
                s[c][r] = p;
                rs[r] += p;
            }
        }
        #pragma unroll
        for (int r = 0; r < 4; r++) {
            rs[r] += __shfl_xor(rs[r], 1);
            rs[r] += __shfl_xor(rs[r], 2);
            rs[r] += __shfl_xor(rs[r], 4);
            rs[r] += __shfl_xor(rs[r], 8);
            l_run[r] = l_run[r] * alpha[r] + rs[r];
        }
        #pragma unroll
        for (int f = 0; f < 4; f++)
            #pragma unroll
            for (int r = 0; r < 4; r++) o[f][r] *= alpha[r];

        #pragma unroll
        for (int c = 0; c < 4; c++)
            #pragma unroll
            for (int r = 0; r < 4; r++)
                p_lds[w][lg * 4 + r][c * 16 + lr] = f2bf(s[c][r]);

        #pragma unroll
        for (int kk = 0; kk < 2; kk++) {
            bf16x8 ap = *(const bf16x8*)(&p_lds[w][lr][kk * 32 + lg * 8]);
            #pragma unroll
            for (int f = 0; f < 4; f++) {
                bf16x8 bv = *(const bf16x8*)(&vt_lds[f * 16 + lr][kk * 32 + lg * 8]);
                o[f] = __builtin_amdgcn_mfma_f32_16x16x32_bf16(ap, bv, o[f], 0, 0, 0);
            }
        }
        __syncthreads();
    }

    float invl[4];
    #pragma unroll
    for (int r = 0; r < 4; r++) invl[r] = 1.f / l_run[r];
    u16* ob = attn_out + ((size_t)b * 2048 + q0 + w * 16 + lg * 4) * 1024 + h * 64 + lr;
    #pragma unroll
    for (int f = 0; f < 4; f++)
        #pragma unroll
        for (int r = 0; r < 4; r++)
            ob[(size_t)r * 1024 + f * 16] = f2bf(o[f][r] * invl[r]);
}

// ---------------- launcher ----------------
extern "C" void kernel_launch(void* const* d_in, const int* in_sizes, int n_in,
                              void* d_out, int out_size, void* d_ws, size_t ws_size,
                              hipStream_t stream) {
    const float* hidden = (const float*)d_in[0];
    const float* enc    = (const float*)d_in[1];
    const float* Wq = (const float*)d_in[2];
    const float* Wk = (const float*)d_in[3];
    const float* Wv = (const float*)d_in[4];
    const float* Wo = (const float*)d_in[5];
    const float* bo = (const float*)d_in[6];
    const float* Wg = (const float*)d_in[7];
    const float* bg = (const float*)d_in[8];
    float* out = (float*)d_out;

    char* ws = (char*)d_ws;
    size_t off = 0;
    auto alloc = [&](size_t bytes) -> char* {
        char* p = ws + off;
        off += (bytes + 255) & ~(size_t)255;
        return p;
    };
    u16* hbf   = (u16*)alloc(4096ull * 1024 * 2);
    u16* ebf   = (u16*)alloc(32768ull * 1024 * 2);
    u16* WqT   = (u16*)alloc(1024ull * 1024 * 2);
    u16* WkvT  = (u16*)alloc(2048ull * 1024 * 2);
    u16* WgT   = (u16*)alloc(1024ull * 1024 * 2);
    u16* WoT   = (u16*)alloc(1024ull * 1024 * 2);
    u16* q_bf  = (u16*)alloc(4096ull * 1024 * 2);
    u16* kvbf  = (u16*)alloc(32768ull * 2048 * 2);
    float* qsum = (float*)alloc(32ull * 64 * 4);
    float* scor = (float*)alloc(32ull * 16384 * 4);
    int* sel    = (int*)alloc(32ull * 2048 * 4);
    u16* vT     = (u16*)alloc(32ull * 64 * 2048 * 2);
    u16* attn   = (u16*)alloc(4096ull * 1024 * 2);
    u16* gate   = (u16*)alloc(4096ull * 1024 * 2);
    (void)ws_size; (void)in_sizes; (void)n_in; (void)out_size;

    cast_bf16_kernel<<<4096, 256, 0, stream>>>(hidden, hbf, 1048576);
    cast_bf16_kernel<<<32768, 256, 0, stream>>>(enc, ebf, 8388608);
    transpose_cast_kernel<<<dim3(32, 32, 5), dim3(32, 8), 0, stream>>>(
        Wq, Wk, Wv, Wg, Wo, WqT, WkvT, WgT, WoT);

    gemm_bf16<0><<<dim3(8, 32), 256, 0, stream>>>(hbf, WqT, 1024, q_bf, nullptr, nullptr, nullptr, nullptr);
    gemm_bf16<0><<<dim3(16, 256), 256, 0, stream>>>(ebf, WkvT, 2048, kvbf, nullptr, nullptr, nullptr, nullptr);

    qsum_kernel<<<32, 256, 0, stream>>>(q_bf, qsum);
    score_kernel<<<dim3(64, 32), 256, 0, stream>>>(kvbf, qsum, scor);
    select_kernel<<<32, 256, 0, stream>>>(scor, sel);
    gather_vt_kernel<<<dim3(32, 32), 256, 0, stream>>>(kvbf, sel, vT);

    attn_kernel<<<dim3(32, 32), 256, 0, stream>>>(q_bf, kvbf, vT, sel, attn);

    gemm_bf16<2><<<dim3(8, 32), 256, 0, stream>>>(attn, WgT, 1024, gate, bg, attn, nullptr, nullptr);
    gemm_bf16<3><<<dim3(8, 32), 256, 0, stream>>>(gate, WoT, 1024, nullptr, bo, nullptr, hidden, out);
}

// Round 2
// 607.122 us; speedup vs baseline: 1.0341x; 1.0341x over previous
//
#include <hip/hip_runtime.h>
#include <hip/hip_bf16.h>

typedef unsigned short u16;
typedef __bf16 bf16x8 __attribute__((ext_vector_type(8)));
typedef float f32x4 __attribute__((ext_vector_type(4)));

__device__ __forceinline__ u16 f2bf(float f) {
    union { float f; unsigned int u; } v; v.f = f;
    unsigned int u = v.u;
    unsigned int r = (u + 0x7fffu + ((u >> 16) & 1u)) >> 16;
    return (u16)r;
}
__device__ __forceinline__ float bf2f(u16 b) {
    union { unsigned int u; float f; } v; v.u = ((unsigned int)b) << 16;
    return v.f;
}

__device__ __forceinline__ void glds16(const u16* g, u16* l) {
    __builtin_amdgcn_global_load_lds(
        (__attribute__((address_space(1))) void*)(g),
        (__attribute__((address_space(3))) void*)(l), 16, 0, 0);
}

// ---------------- cast fp32 -> bf16 (vectorized) ----------------
__global__ __launch_bounds__(256) void cast_bf16_kernel(const float* __restrict__ src,
                                                        u16* __restrict__ dst, int n4) {
    int i = blockIdx.x * 256 + threadIdx.x;
    if (i >= n4) return;
    float4 v = ((const float4*)src)[i];
    ushort4 o;
    o.x = f2bf(v.x); o.y = f2bf(v.y); o.z = f2bf(v.z); o.w = f2bf(v.w);
    ((ushort4*)dst)[i] = o;
}

// ---------------- transpose+cast weights: WT[n][k] = W[k][n] ----------------
__global__ __launch_bounds__(256) void transpose_cast_kernel(
    const float* __restrict__ Wq, const float* __restrict__ Wk, const float* __restrict__ Wv,
    const float* __restrict__ Wg, const float* __restrict__ Wo,
    u16* __restrict__ WqT, u16* __restrict__ WkvT, u16* __restrict__ WgT, u16* __restrict__ WoT) {
    __shared__ float tile[32][33];
    const float* src; u16* dst;
    switch (blockIdx.z) {
        case 0: src = Wq; dst = WqT; break;
        case 1: src = Wk; dst = WkvT; break;
        case 2: src = Wv; dst = WkvT + (size_t)1024 * 1024; break;
        case 3: src = Wg; dst = WgT; break;
        default: src = Wo; dst = WoT; break;
    }
    int n0 = blockIdx.x * 32, k0 = blockIdx.y * 32;
    int tx = threadIdx.x, ty = threadIdx.y;   // (32, 8)
    #pragma unroll
    for (int j = 0; j < 4; j++)
        tile[ty + j * 8][tx] = src[(size_t)(k0 + ty + j * 8) * 1024 + n0 + tx];
    __syncthreads();
    #pragma unroll
    for (int j = 0; j < 4; j++)
        dst[(size_t)(n0 + ty + j * 8) * 1024 + k0 + tx] = f2bf(tile[tx][ty + j * 8]);
}

// ---------------- bf16 MFMA GEMM: C[M,N] = A[M,1024] @ B[N,1024]^T ----------------
template <int EPI>
__global__ __launch_bounds__(256) void gemm_bf16(
    const u16* __restrict__ A, const u16* __restrict__ B, int ldc,
    u16* __restrict__ Cbf, const float* __restrict__ bias,
    const u16* __restrict__ mul_src, const float* __restrict__ add_src,
    float* __restrict__ Cf) {
    constexpr int K = 1024;
    const int tid = threadIdx.x;
    const int w = tid >> 6, l = tid & 63;
    const int lr = l & 15, lg = l >> 4;
    const int wr = w >> 1, wc = w & 1;
    const int m0 = blockIdx.y * 128, n0 = blockIdx.x * 128;

    __shared__ u16 As[128 * 64];
    __shared__ u16 Bs[128 * 64];

    const f32x4 fz = {0.f, 0.f, 0.f, 0.f};
    f32x4 acc[4][4];
    #pragma unroll
    for (int i = 0; i < 4; i++)
        #pragma unroll
        for (int j = 0; j < 4; j++) acc[i][j] = fz;

    const int lane_row = l >> 3;
    const int lane_sl  = l & 7;
    const int src_ch   = lane_sl ^ lane_row;
    const u16* Ab = A + (size_t)(m0 + w * 32 + lane_row) * K + src_ch * 8;
    const u16* Bb = B + (size_t)(n0 + w * 32 + lane_row) * K + src_ch * 8;

    for (int kt = 0; kt < K; kt += 64) {
        __syncthreads();
        #pragma unroll
        for (int j = 0; j < 4; j++) {
            glds16(Ab + (size_t)j * 8 * K + kt, As + (w * 32 + j * 8) * 64);
            glds16(Bb + (size_t)j * 8 * K + kt, Bs + (w * 32 + j * 8) * 64);
        }
        __syncthreads();
        #pragma unroll
        for (int kk = 0; kk < 2; kk++) {
            bf16x8 af[4], bfr[4];
            #pragma unroll
            for (int mi = 0; mi < 4; mi++) {
                int row = wr * 64 + mi * 16 + lr;
                int ch = (kk * 4 + lg) ^ (row & 7);
                af[mi] = *(const bf16x8*)(As + row * 64 + ch * 8);
            }
            #pragma unroll
            for (int ni = 0; ni < 4; ni++) {
                int row = wc * 64 + ni * 16 + lr;
                int ch = (kk * 4 + lg) ^ (row & 7);
                bfr[ni] = *(const bf16x8*)(Bs + row * 64 + ch * 8);
            }
            #pragma unroll
            for (int mi = 0; mi < 4; mi++)
                #pragma unroll
                for (int ni = 0; ni < 4; ni++)
                    acc[mi][ni] = __builtin_amdgcn_mfma_f32_16x16x32_bf16(
                        af[mi], bfr[ni], acc[mi][ni], 0, 0, 0);
        }
    }

    #pragma unroll
    for (int mi = 0; mi < 4; mi++) {
        #pragma unroll
        for (int ni = 0; ni < 4; ni++) {
            #pragma unroll
            for (int r = 0; r < 4; r++) {
                int gm = m0 + wr * 64 + mi * 16 + lg * 4 + r;
                int gn = n0 + wc * 64 + ni * 16 + lr;
                float v = acc[mi][ni][r];
                if (EPI == 0) {
                    Cbf[(size_t)gm * ldc + gn] = f2bf(v);
                } else if (EPI == 2) {
                    float g = v + bias[gn];
                    float a = bf2f(mul_src[(size_t)gm * ldc + gn]);
                    float sg = 1.f / (1.f + __expf(-g));
                    Cbf[(size_t)gm * ldc + gn] = f2bf(a * sg);
                } else {
                    Cf[(size_t)gm * ldc + gn] = v + bias[gn] + add_src[(size_t)gm * ldc + gn];
                }
            }
        }
    }
}

// ---------------- q_summary ----------------
__global__ __launch_bounds__(256) void qsum_kernel(const u16* __restrict__ q_bf,
                                                   float* __restrict__ qsum) {
    int bh = blockIdx.x, b = bh >> 4, h = bh & 15;
    int tid = threadIdx.x, d = tid & 63, c = tid >> 6;
    const u16* base = q_bf + ((size_t)b * 2048 + c) * 1024 + h * 64 + d;
    float acc = 0.f;
    for (int qi = c; qi < 2048; qi += 4) { acc += bf2f(*base); base += 4 * 1024; }
    __shared__ float red[256];
    red[tid] = acc;
    __syncthreads();
    if (tid < 64)
        qsum[bh * 64 + tid] = (red[tid] + red[tid + 64] + red[tid + 128] + red[tid + 192]) * (1.f / 2048.f);
}

// ---------------- selection scores ----------------
__global__ __launch_bounds__(256) void score_kernel(const u16* __restrict__ kv_bf,
                                                    const float* __restrict__ qsum,
                                                    float* __restrict__ score) {
    int bh = blockIdx.y, b = bh >> 4, h = bh & 15;
    __shared__ float qs[64];
    if (threadIdx.x < 64) qs[threadIdx.x] = qsum[bh * 64 + threadIdx.x];
    __syncthreads();
    int kv = blockIdx.x * 256 + threadIdx.x;
    const u16* kr = kv_bf + ((size_t)(b * 16384 + kv)) * 2048 + h * 64;
    float acc = 0.f;
    #pragma unroll
    for (int c = 0; c < 8; c++) {
        uint4 u = *(const uint4*)(kr + c * 8);
        const u16* p = (const u16*)&u;
        #pragma unroll
        for (int j = 0; j < 8; j++) acc += bf2f(p[j]) * qs[c * 8 + j];
    }
    score[(size_t)bh * 16384 + kv] = acc * 0.125f;
}

// ---------------- radix top-2048 select per (b,h) ----------------
__global__ __launch_bounds__(256) void select_kernel(const float* __restrict__ score,
                                                     int* __restrict__ sel_idx) {
    int bh = blockIdx.x;
    const float* sc = score + (size_t)bh * 16384;
    __shared__ int hist[256];
    __shared__ int bc[4];
    int tid = threadIdx.x;
    if (tid == 0) { bc[0] = 0; bc[1] = 2048; bc[2] = 0; bc[3] = 0; }
    __syncthreads();
    for (int shift = 24; shift >= 0; shift -= 8) {
        hist[tid] = 0;
        __syncthreads();
        unsigned int prefix = (unsigned int)bc[0];
        unsigned int hi_mask = (shift == 24) ? 0u : (0xFFFFFFFFu << (shift + 8));
        for (int i = tid; i < 16384; i += 256) {
            unsigned int b = __float_as_uint(sc[i]);
            unsigned int ui = (b & 0x80000000u) ? ~b : (b | 0x80000000u);
            if ((ui & hi_mask) == (prefix & hi_mask))
                atomicAdd(&hist[(ui >> shift) & 0xff], 1);
        }
        __syncthreads();
        if (tid == 0) {
            int want = bc[1], acc = 0, d = 0;
            for (int dd = 255; dd >= 0; dd--) {
                acc += hist[dd];
                if (acc >= want) { d = dd; break; }
            }
            bc[1] = want - (acc - hist[d]);
            bc[0] = (int)(prefix | ((unsigned int)d << shift));
        }
        __syncthreads();
    }
    unsigned int uthr = (unsigned int)bc[0];
    int n_eq = bc[1];
    int base_eq = 2048 - n_eq;
    int* out = sel_idx + (size_t)bh * 2048;
    for (int i = tid; i < 16384; i += 256) {
        unsigned int b = __float_as_uint(sc[i]);
        unsigned int ui = (b & 0x80000000u) ? ~b : (b | 0x80000000u);
        if (ui > uthr) {
            int p = atomicAdd(&bc[2], 1);
            out[p] = i;
        } else if (ui == uthr) {
            int p = atomicAdd(&bc[3], 1);
            if (p < n_eq) out[base_eq + p] = i;
        }
    }
}

// ---------------- gather K_sel (row-major, chunk-swizzled) + V_selT (transposed, chunk-swizzled) ----
// K_sel[bh][t][ (ch^(t&7))*8 + j ] = K[idx[t]][h*64 + ch*8 + j]
// V_selT[bh][d][ (t>>6)*64 + (((t>>3)&7)^(d&7))*8 + (t&7) ] = V[idx[t]][h*64+d]
__global__ __launch_bounds__(256) void gather_kv_kernel(const u16* __restrict__ kv_bf,
                                                        const int* __restrict__ sel_idx,
                                                        u16* __restrict__ k_sel,
                                                        u16* __restrict__ v_selT) {
    int bh = blockIdx.y, b = bh >> 4, h = bh & 15;
    int t0 = blockIdx.x * 64, tid = threadIdx.x;
    __shared__ u16 tile[64][72];
    __shared__ int idx[64];
    if (tid < 64) idx[tid] = sel_idx[(size_t)bh * 2048 + t0 + tid];
    __syncthreads();
    int t = tid >> 2, c4 = tid & 3;
    const u16* src = kv_bf + ((size_t)(b * 16384 + idx[t])) * 2048 + h * 64;
    {   // K: chunks 2c4, 2c4+1, written xor-permuted within the row
        uint4 a0 = *(const uint4*)(src + c4 * 16);
        uint4 a1 = *(const uint4*)(src + c4 * 16 + 8);
        int key = t & 7;
        u16* kd = k_sel + ((size_t)bh * 2048 + t0 + t) * 64;
        *(uint4*)(kd + ((2 * c4) ^ key) * 8) = a0;
        *(uint4*)(kd + ((2 * c4 + 1) ^ key) * 8) = a1;
    }
    {   // V into LDS tile
        const u16* vsrc = src + 1024 + c4 * 16;
        *(uint4*)&tile[t][c4 * 16]     = *(const uint4*)vsrc;
        *(uint4*)&tile[t][c4 * 16 + 8] = *(const uint4*)(vsrc + 8);
    }
    __syncthreads();
    u16* dst = v_selT + (size_t)bh * 64 * 2048;
    #pragma unroll
    for (int rep = 0; rep < 2; rep++) {
        int ch = tid + rep * 256;
        int d = ch >> 3, c = ch & 7;
        union { u16 u[8]; uint4 v; } tmp;
        #pragma unroll
        for (int j = 0; j < 8; j++) tmp.u[j] = tile[c * 8 + j][d];
        *(uint4*)(dst + (size_t)d * 2048 + t0 + ((c ^ (d & 7)) * 8)) = tmp.v;
    }
}

// ---------------- flash attention over compacted selected KV ----------------
__global__ __launch_bounds__(256) void attn_kernel(
    const u16* __restrict__ q_bf, const u16* __restrict__ k_sel,
    const u16* __restrict__ v_selT, u16* __restrict__ attn_out) {
    const int bh = blockIdx.y, b = bh >> 4, h = bh & 15;
    const int q0 = blockIdx.x * 64;
    const int tid = threadIdx.x, w = tid >> 6, l = tid & 63;
    const int lr = l & 15, lg = l >> 4;
    const int lk = lr & 7;
    const float SC = 0.18033688011f;   // 0.125 * log2(e)
    const float THR = 11.0f;           // defer-max threshold (log2 domain)

    __shared__ u16 k_lds[64 * 64];
    __shared__ u16 vt_lds[64 * 64];
    __shared__ __bf16 p_lds[4][16][72];

    const u16* qb = q_bf + ((size_t)b * 2048 + q0 + w * 16 + lr) * 1024 + h * 64;
    bf16x8 qf0 = *(const bf16x8*)(qb + lg * 8);
    bf16x8 qf1 = *(const bf16x8*)(qb + 32 + lg * 8);

    const f32x4 fz = {0.f, 0.f, 0.f, 0.f};
    f32x4 o[4];
    #pragma unroll
    for (int f = 0; f < 4; f++) o[f] = fz;
    float mm[4] = {-1e30f, -1e30f, -1e30f, -1e30f};   // running max, log2-scaled domain
    float l_run[4] = {0.f, 0.f, 0.f, 0.f};

    const u16* kb  = k_sel + (size_t)bh * 2048 * 64;
    const u16* vtb = v_selT + (size_t)bh * 64 * 2048;

    #pragma unroll 1
    for (int it = 0; it < 32; ++it) {
        const int t0 = it * 64;
        // stage K tile rows w*16..w*16+15 (global layout pre-swizzled -> linear copy)
        const u16* ksrc = kb + (size_t)(t0 + w * 16) * 64 + (size_t)l * 8;
        glds16(ksrc,       k_lds + (w * 16) * 64);
        glds16(ksrc + 512, k_lds + (w * 16 + 8) * 64);
        // stage V^T tile rows (d) w*16..w*16+15
        const u16* vsrc = vtb + (size_t)(w * 16 + (l >> 3)) * 2048 + t0 + (l & 7) * 8;
        glds16(vsrc,            vt_lds + (w * 16) * 64);
        glds16(vsrc + 8 * 2048, vt_lds + (w * 16 + 8) * 64);
        __syncthreads();

        // QK^T
        f32x4 s[4];
        #pragma unroll
        for (int c = 0; c < 4; c++) s[c] = fz;
        #pragma unroll
        for (int c = 0; c < 4; c++) {
            const u16* krow = k_lds + (c * 16 + lr) * 64;
            bf16x8 kf0 = *(const bf16x8*)(krow + (lg ^ lk) * 8);
            s[c] = __builtin_amdgcn_mfma_f32_16x16x32_bf16(qf0, kf0, s[c], 0, 0, 0);
            bf16x8 kf1 = *(const bf16x8*)(krow + (((4 + lg) ^ lk)) * 8);
            s[c] = __builtin_amdgcn_mfma_f32_16x16x32_bf16(qf1, kf1, s[c], 0, 0, 0);
        }

        // row max (over 4 regs x 16 lanes)
        float mx[4];
        #pragma unroll
        for (int r = 0; r < 4; r++) {
            float m0 = fmaxf(fmaxf(s[0][r], s[1][r]), fmaxf(s[2][r], s[3][r]));
            m0 = fmaxf(m0, __shfl_xor(m0, 1));
            m0 = fmaxf(m0, __shfl_xor(m0, 2));
            m0 = fmaxf(m0, __shfl_xor(m0, 4));
            m0 = fmaxf(m0, __shfl_xor(m0, 8));
            mx[r] = m0 * SC;
        }
        // defer-max: rescale only when max grew beyond THR
        bool need = false;
        #pragma unroll
        for (int r = 0; r < 4; r++) need = need || (mx[r] > mm[r] + THR);
        if (__any(need)) {
            #pragma unroll
            for (int r = 0; r < 4; r++) {
                float mn = fmaxf(mm[r], mx[r]);
                float al = __builtin_amdgcn_exp2f(mm[r] - mn);
                mm[r] = mn;
                l_run[r] *= al;
                #pragma unroll
                for (int f = 0; f < 4; f++) o[f][r] *= al;
            }
        }
        // P = exp2(s*SC - mm), row sums, store bf16 to LDS
        float rs[4] = {0.f, 0.f, 0.f, 0.f};
        #pragma unroll
        for (int c = 0; c < 4; c++) {
            #pragma unroll
            for (int r = 0; r < 4; r++) {
                float p = __builtin_amdgcn_exp2f(__builtin_fmaf(s[c][r], SC, -mm[r]));
                rs[r] += p;
                p_lds[w][lg * 4 + r][c * 16 + lr] = (__bf16)p;
            }
        }
        #pragma unroll
        for (int r = 0; r < 4; r++) {
            rs[r] += __shfl_xor(rs[r], 1);
            rs[r] += __shfl_xor(rs[r], 2);
            rs[r] += __shfl_xor(rs[r], 4);
            rs[r] += __shfl_xor(rs[r], 8);
            l_run[r] += rs[r];
        }

        // PV
        #pragma unroll
        for (int kk = 0; kk < 2; kk++) {
            bf16x8 ap = *(const bf16x8*)(&p_lds[w][lr][kk * 32 + lg * 8]);
            #pragma unroll
            for (int f = 0; f < 4; f++) {
                const u16* vrow = vt_lds + (f * 16 + lr) * 64;
                bf16x8 bv = *(const bf16x8*)(vrow + (((kk * 4 + lg) ^ lk)) * 8);
                o[f] = __builtin_amdgcn_mfma_f32_16x16x32_bf16(ap, bv, o[f], 0, 0, 0);
            }
        }
        __syncthreads();
    }

    float invl[4];
    #pragma unroll
    for (int r = 0; r < 4; r++) invl[r] = 1.f / l_run[r];
    u16* ob = attn_out + ((size_t)b * 2048 + q0 + w * 16 + lg * 4) * 1024 + h * 64 + lr;
    #pragma unroll
    for (int f = 0; f < 4; f++) {
        #pragma unroll
        for (int r = 0; r < 4; r++) {
            __bf16 hv = (__bf16)(o[f][r] * invl[r]);
            ob[(size_t)r * 1024 + f * 16] = *(u16*)&hv;
        }
    }
}

// ---------------- launcher ----------------
extern "C" void kernel_launch(void* const* d_in, const int* in_sizes, int n_in,
                              void* d_out, int out_size, void* d_ws, size_t ws_size,
                              hipStream_t stream) {
    const float* hidden = (const float*)d_in[0];
    const float* enc    = (const float*)d_in[1];
    const float* Wq = (const float*)d_in[2];
    const float* Wk = (const float*)d_in[3];
    const float* Wv = (const float*)d_in[4];
    const float* Wo = (const float*)d_in[5];
    const float* bo = (const float*)d_in[6];
    const float* Wg = (const float*)d_in[7];
    const float* bg = (const float*)d_in[8];
    float* out = (float*)d_out;

    char* ws = (char*)d_ws;
    size_t off = 0;
    auto alloc = [&](size_t bytes) -> char* {
        char* p = ws + off;
        off += (bytes + 255) & ~(size_t)255;
        return p;
    };
    u16* hbf   = (u16*)alloc(4096ull * 1024 * 2);
    u16* ebf   = (u16*)alloc(32768ull * 1024 * 2);
    u16* WqT   = (u16*)alloc(1024ull * 1024 * 2);
    u16* WkvT  = (u16*)alloc(2048ull * 1024 * 2);
    u16* WgT   = (u16*)alloc(1024ull * 1024 * 2);
    u16* WoT   = (u16*)alloc(1024ull * 1024 * 2);
    u16* q_bf  = (u16*)alloc(4096ull * 1024 * 2);
    u16* kvbf  = (u16*)alloc(32768ull * 2048 * 2);
    float* qsum = (float*)alloc(32ull * 64 * 4);
    float* scor = (float*)alloc(32ull * 16384 * 4);
    int* sel    = (int*)alloc(32ull * 2048 * 4);
    u16* ksel   = (u16*)alloc(32ull * 2048 * 64 * 2);
    u16* vT     = (u16*)alloc(32ull * 64 * 2048 * 2);
    u16* attn   = (u16*)alloc(4096ull * 1024 * 2);
    u16* gate   = (u16*)alloc(4096ull * 1024 * 2);
    (void)ws_size; (void)in_sizes; (void)n_in; (void)out_size;

    cast_bf16_kernel<<<4096, 256, 0, stream>>>(hidden, hbf, 1048576);
    cast_bf16_kernel<<<32768, 256, 0, stream>>>(enc, ebf, 8388608);
    transpose_cast_kernel<<<dim3(32, 32, 5), dim3(32, 8), 0, stream>>>(
        Wq, Wk, Wv, Wg, Wo, WqT, WkvT, WgT, WoT);

    gemm_bf16<0><<<dim3(8, 32), 256, 0, stream>>>(hbf, WqT, 1024, q_bf, nullptr, nullptr, nullptr, nullptr);
    gemm_bf16<0><<<dim3(16, 256), 256, 0, stream>>>(ebf, WkvT, 2048, kvbf, nullptr, nullptr, nullptr, nullptr);

    qsum_kernel<<<32, 256, 0, stream>>>(q_bf, qsum);
    score_kernel<<<dim3(64, 32), 256, 0, stream>>>(kvbf, qsum, scor);
    select_kernel<<<32, 256, 0, stream>>>(scor, sel);
    gather_kv_kernel<<<dim3(32, 32), 256, 0, stream>>>(kvbf, sel, ksel, vT);

    attn_kernel<<<dim3(32, 32), 256, 0, stream>>>(q_bf, ksel, vT, attn);

    gemm_bf16<2><<<dim3(8, 32), 256, 0, stream>>>(attn, WgT, 1024, gate, bg, attn, nullptr, nullptr);
    gemm_bf16<3><<<dim3(8, 32), 256, 0, stream>>>(gate, WoT, 1024, nullptr, bo, nullptr, hidden, out);
}